// Round 10
// baseline (97.833 us; speedup 1.0000x reference)
//
#include <hip/hip_runtime.h>
#include <hip/hip_bf16.h>

#define EPSW 1e-6f

typedef __attribute__((ext_vector_type(4))) float floatx4;
typedef __attribute__((ext_vector_type(4))) unsigned int uintx4;
typedef __attribute__((ext_vector_type(8))) short shortx8;   // 8 bf16 (4 VGPRs)

// round-to-nearest-even float -> bf16 bits (finite inputs)
__device__ __forceinline__ unsigned short f2bf(float f) {
    unsigned int u = __float_as_uint(f);
    u = (u + 0x7fffu + ((u >> 16) & 1u)) >> 16;
    return (unsigned short)u;
}

__device__ __forceinline__ unsigned int pk2(float lo, float hi) {
    return (unsigned int)f2bf(lo) | ((unsigned int)f2bf(hi) << 16);
}

__device__ __forceinline__ uintx4 pk8(floatx4 a, floatx4 b) {
    uintx4 r;
    r.x = pk2(a.x, a.y); r.y = pk2(a.z, a.w);
    r.z = pk2(b.x, b.y); r.w = pk2(b.z, b.w);
    return r;
}

// ---------------------------------------------------------------------------
// gcn_all: SINGLE KERNEL. 256 blocks x 512 threads (8 waves), 1 block/CU.
//   bid = hs*32 + batch (hs = bid>>5: 16-wide h-slice; batch = bid&31).
//   bid%8 = batch%8 -> a batch's 8 h-blocks share one XCD (round-robin
//   dispatch): x[batch] (512 KB) + W (1 MB) stay L2-resident (3 MB < 4 MB).
// Phases (all ordering intra-block via __syncthreads -- no fences, no
// cross-block dependencies, no workspace):
//  P0  issue superchunk 0,1 global loads (registers) -- in flight during P1.
//  P1  M-build IN-BLOCK (redundant, ~0.6 us, hidden under P0 latency):
//      normalized adjacency A in LDS scratch (atomics), M = A@A, written
//      straight to LDS Ms[c*64+n] = M[n][c]. r8-mbuild-proven numerics.
//  P2  K-loop: 8 superchunks of BK=256. r4-PROVEN coalesced staging: thread
//      (kq=t&7, rw=t>>3) reads 4x 32 B of x (8-lane groups = 256 B
//      contiguous row segments) + (t&31, t>>5) reads 32 B of W (32-lane
//      groups = 1 KB contiguous); fp32->bf16 pk8 into double-buffered LDS
//      granules. 2-deep register prefetch, ONE barrier per superchunk
//      (reuse at s+2 transitively ordered by barrier s+1 -- r9-validated).
//      Wave w owns K-chunk w of each superchunk (kg = w*4+q):
//      4 MFMA/superchunk/wave, acc[4 row-tiles] (x rows), B = W h-frag.
//  P3  epilogue (r8-proven): zpart[8][64][17] -> 8-way reduce -> zs;
//      y = bias + M@z via fp32 VALU loop reading Ms. Plain stores.
// LDS: Ms 16 KB + staging 2x40 KB + red 38.25 KB (Abuild aliases zpart
// region) = 134.25 KB < 160 KB.
// ---------------------------------------------------------------------------
__global__ __launch_bounds__(512) void gcn_all(
        const float* __restrict__ x,
        const float* __restrict__ W,
        const int* __restrict__ ei,
        const float* __restrict__ ew,
        const float* __restrict__ bias,
        float* __restrict__ y) {
    __shared__ float Ms[4096];                            // 16 KB, persistent
    __shared__ __align__(16) unsigned char stg[2][40960]; // 80 KB staging
    __shared__ float red[9792];                           // 38.25 KB scratch

    const int t     = threadIdx.x;
    const int bid   = blockIdx.x;
    const int hs    = bid >> 5;         // 0..7
    const int batch = bid & 31;
    const int rbase = batch * 64;
    const int hbase = hs * 16;

    const int wave = t >> 6, lane = t & 63;
    const int m = lane & 15, q = lane >> 4;

    floatx4 acc[4];
#pragma unroll
    for (int rt = 0; rt < 4; ++rt) acc[rt] = (floatx4){0.f, 0.f, 0.f, 0.f};

    // 2-deep staging register sets (compile-time indexed after unroll)
    floatx4 fx[2][4][2];   // [set][sub j][half] : x row t>>3, 32 B per sub
    floatx4 fw[2][2];      // [set][half]        : W row t>>5, 32 B

#define LOADS(s_)                                                             \
    {                                                                         \
        const int p_ = (s_) & 1;                                              \
        _Pragma("unroll")                                                     \
        for (int j_ = 0; j_ < 4; ++j_) {                                      \
            const int k_ = (s_) * 256 + (j_ * 8 + (t & 7)) * 8;               \
            if (k_ < 2000) {                                                  \
                const float* px_ =                                            \
                    x + (size_t)(rbase + (t >> 3)) * 2000 + k_;               \
                fx[p_][j_][0] = *(const floatx4*)px_;                         \
                fx[p_][j_][1] = *(const floatx4*)(px_ + 4);                   \
            } else {                                                          \
                fx[p_][j_][0] = fx[p_][j_][1] =                               \
                    (floatx4){0.f, 0.f, 0.f, 0.f};                            \
            }                                                                 \
        }                                                                     \
        const int kw_ = (s_) * 256 + (t & 31) * 8;                            \
        if (kw_ < 2000) {                                                     \
            const float* pw_ =                                                \
                W + (size_t)(hbase + (t >> 5)) * 2000 + kw_;                  \
            fw[p_][0] = *(const floatx4*)pw_;                                 \
            fw[p_][1] = *(const floatx4*)(pw_ + 4);                           \
        } else {                                                              \
            fw[p_][0] = fw[p_][1] = (floatx4){0.f, 0.f, 0.f, 0.f};            \
        }                                                                     \
    }

#define WRITES(s_)                                                            \
    {                                                                         \
        const int p_ = (s_) & 1;                                              \
        unsigned char* sb_ = stg[p_];                                         \
        _Pragma("unroll")                                                     \
        for (int j_ = 0; j_ < 4; ++j_)                                        \
            *(uintx4*)(sb_ + ((j_ * 8 + (t & 7)) * 64 + (t >> 3)) * 16) =     \
                pk8(fx[p_][j_][0], fx[p_][j_][1]);                            \
        *(uintx4*)(sb_ + 32768 + ((t & 31) * 16 + (t >> 5)) * 16) =           \
            pk8(fw[p_][0], fw[p_][1]);                                        \
    }

    // ---- P0: first two superchunks' loads in flight -----------------------
    LOADS(0);
    LOADS(1);

    // ---- P1: in-block M-build (hidden under P0 HBM latency) ---------------
    {
        float* A    = red;              // 4096 f, A[n][k]
        float* deg  = red + 4096;
        float* dinv = deg + 64;
        if (t < 64) deg[t] = 1.0f;      // self-loop pre-added
        for (int i = t; i < 4096; i += 512) A[i] = 0.0f;
        __syncthreads();
        const int* srcp = ei;
        const int* dstp = ei + 4096;
#pragma unroll
        for (int i = 0; i < 8; ++i) {
            const int e = i * 512 + t;
            float w = ew[e];
            w = (w <= 0.0f) ? EPSW : w;
            atomicAdd(&deg[dstp[e]], w);
        }
        __syncthreads();
        if (t < 64) dinv[t] = 1.0f / sqrtf(deg[t]);
        __syncthreads();
#pragma unroll
        for (int i = 0; i < 8; ++i) {
            const int e = i * 512 + t;
            float w = ew[e];
            w = (w <= 0.0f) ? EPSW : w;
            const int s = srcp[e], d = dstp[e];
            atomicAdd(&A[d * 64 + s], dinv[s] * w * dinv[d]);
        }
        if (t < 64) atomicAdd(&A[t * 64 + t], dinv[t] * dinv[t]);
        __syncthreads();
        const int c   = t & 63;             // lane-varying
        const int n0m = (t >> 6) * 8;       // wave-uniform, 8 rows/thread
        float s[8];
#pragma unroll
        for (int j = 0; j < 8; ++j) s[j] = 0.0f;
#pragma unroll 8
        for (int k = 0; k < 64; ++k) {
            const float akc = A[k * 64 + c];
#pragma unroll
            for (int j = 0; j < 8; ++j) s[j] += A[(n0m + j) * 64 + k] * akc;
        }
#pragma unroll
        for (int j = 0; j < 8; ++j) Ms[c * 64 + n0m + j] = s[j];
        __syncthreads();                    // Ms published; red free for P3
    }

    // ---- P2: K-loop, 8 superchunks ----------------------------------------
#pragma unroll
    for (int s = 0; s < 8; ++s) {
        WRITES(s);                       // fine-grained vmcnt on set s&1
        if (s < 6) LOADS(s + 2);         // keep ~2 superchunks in flight
        __syncthreads();                 // publish buf s&1; reuse at s+2 is
                                         // transitively ordered by barrier s+1
        const unsigned char* sb = stg[s & 1];
        const int kg = wave * 4 + q;     // this wave's K-chunk granule col
        shortx8 af[4];
#pragma unroll
        for (int rt = 0; rt < 4; ++rt)
            af[rt] = *(const shortx8*)(sb + (kg * 64 + rt * 16 + m) * 16);
        const shortx8 bf = *(const shortx8*)(sb + 32768 + (kg * 16 + m) * 16);
#pragma unroll
        for (int rt = 0; rt < 4; ++rt)
            acc[rt] = __builtin_amdgcn_mfma_f32_16x16x32_bf16(
                af[rt], bf, acc[rt], 0, 0, 0);
    }
#undef LOADS
#undef WRITES

    // ---- P3: reduce 8 wave-partials, apply M, store y ---------------------
    // C/D layout: local node n = rt*16 + q*4 + v, local h = m.
    float* zw = red + wave * 1088;       // [64][17]
#pragma unroll
    for (int rt = 0; rt < 4; ++rt)
#pragma unroll
        for (int v = 0; v < 4; ++v)
            zw[(rt * 16 + q * 4 + v) * 17 + m] = acc[rt][v];
    __syncthreads();

    float* zs = red + 8704;              // [64][17]
#pragma unroll
    for (int i = 0; i < 2; ++i) {
        const int idx = i * 512 + t;
        const int row = idx >> 4, hh = idx & 15;
        float ssum = 0.0f;
#pragma unroll
        for (int w = 0; w < 8; ++w) ssum += red[w * 1088 + row * 17 + hh];
        zs[row * 17 + hh] = ssum;
    }
    __syncthreads();

    const int h  = t & 15;
    const int n0 = (t >> 4) * 2;         // 2 output rows per thread
    float s0 = 0.0f, s1 = 0.0f;
#pragma unroll 8
    for (int mm = 0; mm < 64; ++mm) {
        const float zv = zs[mm * 17 + h];
        s0 += Ms[mm * 64 + n0]     * zv; // Ms[mm*64+n] = M[n][mm]
        s1 += Ms[mm * 64 + n0 + 1] * zv;
    }
    const float bv = bias[hbase + h];
    float* yp = y + (size_t)batch * 8192 + (size_t)n0 * 128 + hbase + h;
    yp[0]   = bv + s0;
    yp[128] = bv + s1;
}

extern "C" void kernel_launch(void* const* d_in, const int* in_sizes, int n_in,
                              void* d_out, int out_size, void* d_ws, size_t ws_size,
                              hipStream_t stream) {
    const float* x    = (const float*)d_in[0];   // (2048, 2000) fp32 (flat view)
    const int*   ei   = (const int*)d_in[1];     // (2, 4096)
    const float* ew   = (const float*)d_in[2];   // (4096,)
    const float* W    = (const float*)d_in[3];   // (128, 2000) fp32
    const float* bias = (const float*)d_in[4];   // (128,)
    float* y = (float*)d_out;                    // (32, 64, 128) fp32

    gcn_all<<<256, 512, 0, stream>>>(x, W, ei, ew, bias, y);
}

// Round 11
// 90.714 us; speedup vs baseline: 1.0785x; 1.0785x over previous
//
#include <hip/hip_runtime.h>
#include <hip/hip_bf16.h>

#define EPSW 1e-6f

typedef __attribute__((ext_vector_type(4))) float floatx4;
typedef __attribute__((ext_vector_type(4))) unsigned int uintx4;
typedef __attribute__((ext_vector_type(8))) short shortx8;   // 8 bf16 (4 VGPRs)

// round-to-nearest-even float -> bf16 bits (finite inputs)
__device__ __forceinline__ unsigned short f2bf(float f) {
    unsigned int u = __float_as_uint(f);
    u = (u + 0x7fffu + ((u >> 16) & 1u)) >> 16;
    return (unsigned short)u;
}

__device__ __forceinline__ unsigned int pk2(float lo, float hi) {
    return (unsigned int)f2bf(lo) | ((unsigned int)f2bf(hi) << 16);
}

__device__ __forceinline__ uintx4 pk8(floatx4 a, floatx4 b) {
    uintx4 r;
    r.x = pk2(a.x, a.y); r.y = pk2(a.z, a.w);
    r.z = pk2(b.x, b.y); r.w = pk2(b.z, b.w);
    return r;
}

// ---------------------------------------------------------------------------
// gemm_mt: 256 blocks x 512 threads (8 waves) -- EXACTLY 1 block/CU, no
// scheduling tail. Body is r4's proven GEMM (88.6 us best), unchanged:
//   ks = bid&7 (K-slice of 256; round-robin dispatch clusters same-ks blocks
//   per XCD -> W slice L2-resident), rt2 = bid>>3 (rows rt2*64..+63).
// A (x) and B (W) reg-staged fp32 with fused bf16 convert into
// double-buffered LDS granules; 4 chunks of BK=64; 1-deep register prefetch;
// 2 barriers per chunk. Wave w owns h-tile w; acc[4 row-tiles]; 16
// MFMA/chunk/wave. Epilogue: fp32 partials to zp[ks][row][h].
//
// CHANGE vs r4 (the tail fix): the Mt = (A@A)^T build, which was blocks
// 256..259 (a 4-block SECOND scheduling round that serialized a full extra
// block-duration onto the kernel's critical path), is folded into blocks
// 0..3 AFTER their gemm epilogue, reusing the then-dead 48 KB smem. Those 4
// blocks run ~2 us longer than their siblings -- inside the block-finish
// spread -- instead of costing a whole extra round. Mt->apply_M ordering is
// the kernel boundary (no fences; r3 lesson).
// ---------------------------------------------------------------------------
__global__ __launch_bounds__(512) void gemm_mt(
        const float* __restrict__ x,
        const float* __restrict__ W,
        const int* __restrict__ ei,
        const float* __restrict__ ew,
        float* __restrict__ zp,
        float* __restrict__ Mt) {
    __shared__ __align__(16) unsigned char smem[2][24576];  // 48 KB
    const int bid = blockIdx.x;
    const int t   = threadIdx.x;

    // ---- GEMM (all 256 blocks) -------------------------------------------
    const int ks    = bid & 7;          // K-slice (XCD-clustered)
    const int rt2   = bid >> 3;         // 0..31
    const int rbase = rt2 * 64;
    const int kbase = ks * 256;

    const int wave = t >> 6, lane = t & 63;
    const int m = lane & 15, q = lane >> 4;
    const int kq = t & 7;               // staging granule col 0..7
    const int rw = t >> 3;              // staging row 0..63

    floatx4 acc[4];
#pragma unroll
    for (int rt = 0; rt < 4; ++rt) acc[rt] = (floatx4){0.f, 0.f, 0.f, 0.f};

    floatx4 va0, va1, wb00, wb01, wb10, wb11;  // staged fp32 (A row + 2 W rows)

#define LOADC(c)                                                              \
    {                                                                         \
        const int k_ = kbase + (c) * 64 + kq * 8;                             \
        if (k_ < 2000) {                                                      \
            const float* pa_ = x + (size_t)(rbase + rw) * 2000 + k_;          \
            const float* p0_ = W + (size_t)rw * 2000 + k_;                    \
            const float* p1_ = W + (size_t)(rw + 64) * 2000 + k_;             \
            va0  = *(const floatx4*)pa_;  va1  = *(const floatx4*)(pa_ + 4);  \
            wb00 = *(const floatx4*)p0_;  wb01 = *(const floatx4*)(p0_ + 4);  \
            wb10 = *(const floatx4*)p1_;  wb11 = *(const floatx4*)(p1_ + 4);  \
        } else {                                                              \
            va0 = va1 = wb00 = wb01 = wb10 = wb11 =                           \
                (floatx4){0.f, 0.f, 0.f, 0.f};                                \
        }                                                                     \
    }

#define WRITEC(c)                                                             \
    {                                                                         \
        unsigned char* sb_ = smem[(c) & 1];                                   \
        *(uintx4*)(sb_ + kq * 1024 + rw * 16)               = pk8(va0, va1);  \
        *(uintx4*)(sb_ + 8192 + kq * 2048 + rw * 16)        = pk8(wb00, wb01);\
        *(uintx4*)(sb_ + 8192 + kq * 2048 + (rw + 64) * 16) = pk8(wb10, wb11);\
    }

    LOADC(0);
    for (int c = 0; c < 4; ++c) {
        WRITEC(c);                       // compiler waits vmcnt per register
        if (c < 3) LOADC(c + 1);         // next chunk's HBM latency overlaps
        __syncthreads();                 // all staging writes published
        const unsigned char* sb = smem[c & 1];
#pragma unroll
        for (int p = 0; p < 2; ++p) {
            const int kgq = p * 4 + q;
            shortx8 af[4];
#pragma unroll
            for (int rt = 0; rt < 4; ++rt)
                af[rt] = *(const shortx8*)(sb + kgq * 1024 + (rt * 16 + m) * 16);
            const shortx8 bf = *(const shortx8*)(sb + 8192 + kgq * 2048 +
                                                 (wave * 16 + m) * 16);
#pragma unroll
            for (int rt = 0; rt < 4; ++rt)
                acc[rt] = __builtin_amdgcn_mfma_f32_16x16x32_bf16(
                    af[rt], bf, acc[rt], 0, 0, 0);
        }
        __syncthreads();                 // reads of buf c done before reuse
    }
#undef LOADC
#undef WRITEC

    // epilogue: partial z. C/D layout: row = q*4+v, col = m.
    float* zslice = zp + ((size_t)ks * 2048 + rbase) * 128;
    const int h = wave * 16 + m;
#pragma unroll
    for (int rt = 0; rt < 4; ++rt) {
#pragma unroll
        for (int v = 0; v < 4; ++v) {
            const int n = rt * 16 + q * 4 + v;
            zslice[n * 128 + h] = acc[rt][v];
        }
    }

    // ---- Mt build, folded into blocks 0..3 (smem is dead here) ------------
    if (bid < 4) {
        __syncthreads();                       // all K-loop smem reads done
        const int bm = bid;                    // n-slice [bm*16, bm*16+16)
        float* A    = (float*)smem;            // 4096 f, A[n][k]
        float* deg  = A + 4096;
        float* dinv = deg + 64;
        if (t < 64) deg[t] = 1.0f;             // self-loop pre-added
        for (int i = t; i < 4096; i += 512) A[i] = 0.0f;
        __syncthreads();
        const int* srcp = ei;
        const int* dstp = ei + 4096;
#pragma unroll
        for (int i = 0; i < 8; ++i) {
            const int e = i * 512 + t;
            float w = ew[e];
            w = (w <= 0.0f) ? EPSW : w;
            atomicAdd(&deg[dstp[e]], w);
        }
        __syncthreads();
        if (t < 64) dinv[t] = 1.0f / sqrtf(deg[t]);
        __syncthreads();
#pragma unroll
        for (int i = 0; i < 8; ++i) {
            const int e = i * 512 + t;
            float w = ew[e];
            w = (w <= 0.0f) ? EPSW : w;
            const int s = srcp[e], d = dstp[e];
            atomicAdd(&A[d * 64 + s], dinv[s] * w * dinv[d]);
        }
        if (t < 64) atomicAdd(&A[t * 64 + t], dinv[t] * dinv[t]);
        __syncthreads();
        const int c  = t & 63;
        const int n0 = bm * 16 + (t >> 6);
        const int n1 = n0 + 8;
        float s0 = 0.0f, s1 = 0.0f;
#pragma unroll 8
        for (int k = 0; k < 64; ++k) {
            const float akc = A[k * 64 + c];
            s0 += A[n0 * 64 + k] * akc;
            s1 += A[n1 * 64 + k] * akc;
        }
        Mt[c * 64 + n0] = s0;
        Mt[c * 64 + n1] = s1;
    }
}

// ---------------------------------------------------------------------------
// apply_M: y[b][n][h] = bias[h] + sum_m M[n][m] * (sum_ks zp[ks][b*64+m][h])
// Grid (32 b, 8 h-chunks of 16) x 256 thr = 256 blocks (no tail).
// ---------------------------------------------------------------------------
__global__ __launch_bounds__(256) void apply_M(const float* __restrict__ zp,
                                               const float* __restrict__ Mtg,
                                               const float* __restrict__ bias,
                                               float* __restrict__ y) {
    __shared__ float Ms[4096];
    __shared__ float zs[64][16];
    const int b  = blockIdx.x;
    const int hc = blockIdx.y;
    const int t  = threadIdx.x;
#pragma unroll
    for (int i = 0; i < 16; ++i) Ms[i * 256 + t] = Mtg[i * 256 + t];
#pragma unroll
    for (int i = 0; i < 4; ++i) {
        const int idx = i * 256 + t;
        const int mr = idx >> 4, hh = idx & 15;
        float s = 0.0f;
#pragma unroll
        for (int ks = 0; ks < 8; ++ks)
            s += zp[((size_t)ks * 2048 + b * 64 + mr) * 128 + hc * 16 + hh];
        zs[mr][hh] = s;
    }
    __syncthreads();
    const int h  = t & 15;
    const int n0 = (t >> 4) * 4;
    const float bv = bias[hc * 16 + h];
    float s0 = bv, s1 = bv, s2 = bv, s3 = bv;
#pragma unroll
    for (int mm = 0; mm < 64; ++mm) {
        const float zv = zs[mm][h];
        s0 += Ms[mm * 64 + n0 + 0] * zv;
        s1 += Ms[mm * 64 + n0 + 1] * zv;
        s2 += Ms[mm * 64 + n0 + 2] * zv;
        s3 += Ms[mm * 64 + n0 + 3] * zv;
    }
    float* yp = y + (size_t)b * 8192 + (size_t)n0 * 128 + hc * 16 + h;
    yp[0]   = s0;
    yp[128] = s1;
    yp[256] = s2;
    yp[384] = s3;
}

extern "C" void kernel_launch(void* const* d_in, const int* in_sizes, int n_in,
                              void* d_out, int out_size, void* d_ws, size_t ws_size,
                              hipStream_t stream) {
    const float* x    = (const float*)d_in[0];   // (2048, 2000) fp32 (flat view)
    const int*   ei   = (const int*)d_in[1];     // (2, 4096)
    const float* ew   = (const float*)d_in[2];   // (4096,)
    const float* W    = (const float*)d_in[3];   // (128, 2000) fp32
    const float* bias = (const float*)d_in[4];   // (128,)
    float* y = (float*)d_out;                    // (32, 64, 128) fp32

    float* zp = (float*)d_ws;                    // 8*2048*128 f (8 MB)
    float* Mt = zp + 2097152;                    // 4096 f

    gemm_mt<<<256, 512, 0, stream>>>(x, W, ei, ew, zp, Mt);
    apply_M<<<dim3(32, 8), 256, 0, stream>>>(zp, Mt, bias, y);
}